// Round 18
// baseline (970.655 us; speedup 1.0000x reference)
//
#include <hip/hip_runtime.h>
#include <stdint.h>

#define SEQ 2048
#define DM  1024
#define NH  16
#define HD  64
#define FFD 4096
#define TOK 8192

typedef __bf16 bf16x8 __attribute__((ext_vector_type(8)));
typedef float  f32x4  __attribute__((ext_vector_type(4)));
typedef float  f32x16 __attribute__((ext_vector_type(16)));
typedef unsigned short u16x8 __attribute__((ext_vector_type(8)));
typedef unsigned short u16x4 __attribute__((ext_vector_type(4)));
typedef unsigned int   u32x4 __attribute__((ext_vector_type(4)));

__device__ __forceinline__ unsigned short f2bf(float f) {
  unsigned u = __builtin_bit_cast(unsigned, f);
  u += 0x7fffu + ((u >> 16) & 1u);
  return (unsigned short)(u >> 16);
}
__device__ __forceinline__ float bf2f(unsigned short h) {
  return __builtin_bit_cast(float, ((unsigned)h) << 16);
}
__device__ __forceinline__ f32x4 mfma16(bf16x8 a, bf16x8 b, f32x4 c) {
  return __builtin_amdgcn_mfma_f32_16x16x32_bf16(a, b, c, 0, 0, 0);
}
__device__ __forceinline__ f32x16 mfma32(bf16x8 a, bf16x8 b, f32x16 c) {
  return __builtin_amdgcn_mfma_f32_32x32x16_bf16(a, b, c, 0, 0, 0);
}
__device__ __forceinline__ unsigned cvtpk(float lo, float hi) {
  unsigned r;
  asm("v_cvt_pk_bf16_f32 %0, %1, %2" : "=v"(r) : "v"(lo), "v"(hi));
  return r;
}
__device__ __forceinline__ void gld_lds16(void* lds, const void* g) {
  __builtin_amdgcn_global_load_lds((__attribute__((address_space(1))) void*)g,
                                   (__attribute__((address_space(3))) void*)lds,
                                   16, 0, 0);
}

// ---------------- elementwise casts ----------------
__global__ __launch_bounds__(256) void concat_cast(
    const float* __restrict__ kq, const float* __restrict__ v,
    unsigned short* __restrict__ X) {
  int i = (blockIdx.x * 256 + threadIdx.x) * 4;   // over TOK*DM
  int tkn = i >> 10;
  int c = i & 1023;
  const float* s = (c < 512) ? (kq + (size_t)tkn * 512 + c)
                             : (v  + (size_t)tkn * 512 + (c - 512));
  f32x4 f = *(const f32x4*)s;
  u16x4 o = { f2bf(f[0]), f2bf(f[1]), f2bf(f[2]), f2bf(f[3]) };
  *(u16x4*)&X[i] = o;
}

// All 5 weight casts in ONE kernel. dst1 = Wk|Wq|Wv contiguous (3M elems),
// dst2 = W1|W2 contiguous (8M elems). Segment branch is wave-uniform.
__global__ __launch_bounds__(256) void castW5(
    const float* __restrict__ Wk, const float* __restrict__ Wq,
    const float* __restrict__ Wv, const float* __restrict__ W1,
    const float* __restrict__ W2, unsigned short* __restrict__ dst1,
    unsigned short* __restrict__ dst2) {
  int e = (blockIdx.x * 256 + threadIdx.x) * 4;   // over 11,534,336 elems
  const float* src;
  unsigned short* dst;
  if (e < 3145728) {
    src = (e < 1048576) ? (Wk + e)
        : (e < 2097152) ? (Wq + (e - 1048576))
                        : (Wv + (e - 2097152));
    dst = dst1 + e;
  } else {
    int e2 = e - 3145728;
    src = (e2 < 4194304) ? (W1 + e2) : (W2 + (e2 - 4194304));
    dst = dst2 + e2;
  }
  f32x4 f = *(const f32x4*)src;
  u16x4 o = { f2bf(f[0]), f2bf(f[1]), f2bf(f[2]), f2bf(f[3]) };
  *(u16x4*)dst = o;
}

__global__ __launch_bounds__(256) void bias3(
    const float* __restrict__ a, const float* __restrict__ b,
    const float* __restrict__ c, float* __restrict__ o) {
  int i = blockIdx.x * 256 + threadIdx.x;
  if (i < 1024) o[i] = a[i];
  else if (i < 2048) o[i] = b[i - 1024];
  else if (i < 3072) o[i] = c[i - 2048];
}

// ---------------- counted-pipeline GEMM (R10/R15-verified) ------------------
// BM x 256 tile, BK=64, 512 threads (8 waves 2M x 4N). Double-buffered LDS.
// Per K-tile: vmcnt(0); s_barrier; stage(t+1) into other buffer; ds_read+MFMA.
// T2 XOR swizzle -> bank-conflict 0. XCD 2D-patch mapping -> FETCH ~2x unique.
// 7 schedule variants (R7-R17) all land 103-128 us for FFN1 -> schedule is
// NOT the binding constraint; this is the verified-best simple form.
// EPI: 0 f32 | 1 bf16 | 2 exact-GELU bf16 | 5 fused-QKV.
template<int BM, int EPI>
__global__ __launch_bounds__(512, 2) void gemm256(
    const unsigned short* __restrict__ A, const unsigned short* __restrict__ B,
    const float* __restrict__ bias, void* __restrict__ Cout,
    void* __restrict__ CoutQ, void* __restrict__ CoutV, void* __restrict__ CoutVI,
    int M, int N, int K, int PR, int PC, int NPC) {
  constexpr int MF = BM / 32;       // per-wave M frags (8 | 4)
  constexpr int MG = MF / 4;        // MFMA groups (2 | 1)
  extern __shared__ __align__(16) unsigned short lds[];
  unsigned short* Asm0 = lds;                     // [2][BM*64]
  unsigned short* Bsm0 = lds + 2 * BM * 64;       // [2][256*64]
  const int tid = threadIdx.x;
  const int w = tid >> 6, l = tid & 63, lr = l & 15, lg = l >> 4;
  const int wm = w >> 2, wn = w & 3;
  const int bid = blockIdx.x;
  const int xcd = bid & 7;
  const int i = bid >> 3;
  const int patch_r = xcd / NPC, patch_c = xcd % NPC;
  const int bm = (patch_r * PR + (i % PR)) * BM;
  const int bn = (patch_c * PC + (i / PR)) * 256;
  const int NT = K >> 6;
  const int srow = tid >> 3;
  const int sc8  = tid & 7;

  f32x4 acc[MF][4] = {};

  auto stage = [&](int kt, int bb) {
    unsigned short* da = Asm0 + bb * (BM * 64);
    unsigned short* db = Bsm0 + bb * (256 * 64);
#pragma unroll
    for (int p = 0; p < BM / 64; ++p) {
      int row = p * 64 + srow;
      gld_lds16(da + (p * 512 + w * 64) * 8,
                &A[(size_t)(bm + row) * K + kt * 64 + ((sc8 ^ (row & 7)) << 3)]);
    }
#pragma unroll
    for (int p = 0; p < 4; ++p) {
      int row = p * 64 + srow;
      gld_lds16(db + (p * 512 + w * 64) * 8,
                &B[(size_t)(bn + row) * K + kt * 64 + ((sc8 ^ (row & 7)) << 3)]);
    }
  };

  stage(0, 0);

  for (int t = 0; t < NT; ++t) {
    asm volatile("s_waitcnt vmcnt(0)" ::: "memory");   // stage(t) complete
    __builtin_amdgcn_s_barrier();                      // all waves' stage(t) done
    if (t + 1 < NT) stage(t + 1, (t + 1) & 1);         // full-tile lead
    const unsigned short* As = Asm0 + (t & 1) * (BM * 64);
    const unsigned short* Bs = Bsm0 + (t & 1) * (256 * 64);
    bf16x8 bv[4][2];
#pragma unroll
    for (int fn = 0; fn < 4; ++fn)
#pragma unroll
      for (int kk = 0; kk < 2; ++kk) {
        int row = wn * 64 + fn * 16 + lr;
        int c8 = (kk * 4 + lg) ^ (row & 7);
        bv[fn][kk] = *(const bf16x8*)&Bs[row * 64 + c8 * 8];
      }
#pragma unroll
    for (int mg = 0; mg < MG; ++mg) {
      bf16x8 av[4][2];
#pragma unroll
      for (int fr = 0; fr < 4; ++fr)
#pragma unroll
        for (int kk = 0; kk < 2; ++kk) {
          int row = wm * (BM / 2) + (mg * 4 + fr) * 16 + lr;
          int c8 = (kk * 4 + lg) ^ (row & 7);
          av[fr][kk] = *(const bf16x8*)&As[row * 64 + c8 * 8];
        }
      __builtin_amdgcn_s_setprio(1);
#pragma unroll
      for (int fr = 0; fr < 4; ++fr)
#pragma unroll
        for (int nf = 0; nf < 4; ++nf)
#pragma unroll
          for (int kk = 0; kk < 2; ++kk)
            acc[mg * 4 + fr][nf] = mfma16(av[fr][kk], bv[nf][kk], acc[mg * 4 + fr][nf]);
      __builtin_amdgcn_s_setprio(0);
    }
  }
  // ---- epilogue ----
#pragma unroll
  for (int mf = 0; mf < MF; ++mf) {
    int row0 = bm + wm * (BM / 2) + mf * 16 + lg * 4;
#pragma unroll
    for (int nf = 0; nf < 4; ++nf) {
      int col = bn + wn * 64 + nf * 16 + lr;
      float bcol = bias[col];
#pragma unroll
      for (int r = 0; r < 4; ++r) {
        float vv = acc[mf][nf][r] + bcol;
        int row = row0 + r;
        if (EPI == 2) vv = 0.5f * vv * (1.0f + erff(vv * 0.70710678118654752f));
        if (EPI == 0) {
          ((float*)Cout)[(size_t)row * N + col] = vv;
        } else if (EPI == 5) {
          int third = col >> 10, c = col & 1023;
          unsigned short hv = f2bf(vv);
          int bb = row >> 11, tt = row & 2047;
          if (third == 0) {          // K -> KI[bh][dc16][tok][16]
            int hh = c >> 6, dc = (c >> 4) & 3, dl = c & 15;
            ((unsigned short*)Cout)[((((size_t)(bb * 16 + hh) * 4 + dc) * 2048 + tt) << 4) + dl] = hv;
          } else if (third == 1) {   // Q rows
            ((unsigned short*)CoutQ)[(size_t)row * 1024 + c] = hv;
          } else {                   // V rows + VI[bh][kt16][d][16]
            ((unsigned short*)CoutV)[(size_t)row * 1024 + c] = hv;
            int hh = c >> 6, d = c & 63;
            ((unsigned short*)CoutVI)[((((size_t)(bb * 16 + hh) * 128 + (tt >> 4)) * 64 + d) << 4) + (tt & 15)] = hv;
          }
        } else {
          ((unsigned short*)Cout)[(size_t)row * N + col] = f2bf(vv);
        }
      }
    }
  }
}

// ---------------- causal flash attention, split-K two-wave merge (R16) ------
// launch_bounds (128,6): lift the occupancy cap 8 -> ~11-12 blocks/CU
// (LDS 14 KB/block permits 11; VGPR squeezed to <=85). ~22 waves/CU of
// latency hiding vs 8 before. Everything else identical to R16.
__global__ __launch_bounds__(128, 6) void attn_kernel(
    const unsigned short* __restrict__ Q, const unsigned short* __restrict__ KI,
    const unsigned short* __restrict__ VI, unsigned short* __restrict__ O) {
  __shared__ __align__(16) unsigned short T[32 * 72];
  __shared__ __align__(16) float O1f[32][68];
  __shared__ float M1[64], L1[64];
  const int tid = threadIdx.x;
  const int w = tid >> 6, l = tid & 63;
  const int q32 = l & 31;
  const int g = l >> 5;
  const int x = blockIdx.x;
  const int bh = (x & 7) * 8 + (x >> 3);    // XCD-cluster same-head blocks
  const int b = bh >> 4, h = bh & 15;
  const int u = 63 - (int)blockIdx.y;       // heavy units first
  const int nt = u + 1;
  const int nh = (nt + 1) >> 1;             // wave 0 tile count
  const int jbeg = w ? nh : 0;
  const int jend = w ? nt : nh;
  const size_t tok0 = (size_t)b * SEQ;
  const size_t hoff = (size_t)h * 64;
  const unsigned short* Kp = KI + (size_t)bh * 4 * SEQ * 16;
  const unsigned short* Vp = VI + (size_t)bh * 128 * 64 * 16;

  const int q0 = u * 32;
  const int qg = q0 + q32;            // this lane's q row

  bf16x8 qf[4];
#pragma unroll
  for (int ks = 0; ks < 4; ++ks)
    qf[ks] = *(const bf16x8*)&Q[(tok0 + qg) * DM + hoff + ks * 16 + g * 8];

  f32x16 ot0 = {}, ot1 = {};
  float m = -3.0e38f, lden = 0.f;

  if (jbeg < jend) {
    bf16x8 kf[4], vf[4];
#pragma unroll
    for (int ks = 0; ks < 4; ++ks)
      kf[ks] = *(const bf16x8*)&Kp[((size_t)ks * SEQ + jbeg * 32 + q32) * 16 + g * 8];
#pragma unroll
    for (int dt = 0; dt < 2; ++dt)
#pragma unroll
      for (int s = 0; s < 2; ++s)
        vf[dt * 2 + s] = *(const bf16x8*)&Vp[(((size_t)jbeg * 2 + s) * 64 + dt * 32 + q32) * 16 + g * 8];

#pragma unroll 1
    for (int j = jbeg; j < jend; ++j) {
      f32x16 st = {};
      __builtin_amdgcn_s_setprio(1);
#pragma unroll
      for (int ks = 0; ks < 4; ++ks) st = mfma32(kf[ks], qf[ks], st);
      __builtin_amdgcn_s_setprio(0);
      const int jn = (j + 1 < jend) ? j + 1 : j;
      bf16x8 kn[4], vn[4];
#pragma unroll
      for (int ks = 0; ks < 4; ++ks)
        kn[ks] = *(const bf16x8*)&Kp[((size_t)ks * SEQ + jn * 32 + q32) * 16 + g * 8];
#pragma unroll
      for (int dt = 0; dt < 2; ++dt)
#pragma unroll
        for (int s = 0; s < 2; ++s)
          vn[dt * 2 + s] = *(const bf16x8*)&Vp[(((size_t)jn * 2 + s) * 64 + dt * 32 + q32) * 16 + g * 8];
      if (j == u) {
#pragma unroll
        for (int r = 0; r < 16; ++r) {
          int kg = j * 32 + (r & 3) + 8 * (r >> 2) + 4 * g;
          if (kg > qg) st[r] = -3.0e38f;
        }
      }
      float x0 = fmaxf(st[0], st[1]),  x1 = fmaxf(st[2], st[3]);
      float x2 = fmaxf(st[4], st[5]),  x3 = fmaxf(st[6], st[7]);
      float x4 = fmaxf(st[8], st[9]),  x5 = fmaxf(st[10], st[11]);
      float x6 = fmaxf(st[12], st[13]), x7 = fmaxf(st[14], st[15]);
      x0 = fmaxf(x0, x1); x2 = fmaxf(x2, x3); x4 = fmaxf(x4, x5); x6 = fmaxf(x6, x7);
      x0 = fmaxf(x0, x2); x4 = fmaxf(x4, x6);
      float pmax = fmaxf(x0, x4);
      if (__any(pmax - m > 8.0f)) {
        float pp = fmaxf(pmax, __shfl_xor(pmax, 32, 64));
        float mnew = fmaxf(m, pp);
        float sc = __expf(m - mnew);
#pragma unroll
        for (int r = 0; r < 16; ++r) { ot0[r] *= sc; ot1[r] *= sc; }
        lden *= sc;
        m = mnew;
      }
      float p[16];
#pragma unroll
      for (int r = 0; r < 16; ++r) p[r] = __expf(st[r] - m);
      {
        float s0 = p[0] + p[1], s1 = p[2] + p[3], s2 = p[4] + p[5], s3 = p[6] + p[7];
        float s4 = p[8] + p[9], s5 = p[10] + p[11], s6 = p[12] + p[13], s7 = p[14] + p[15];
        s0 += s1; s2 += s3; s4 += s5; s6 += s7;
        s0 += s2; s4 += s6;
        lden += s0 + s4;
      }
      unsigned c0 = cvtpk(p[0], p[1]),   c1 = cvtpk(p[2], p[3]);
      unsigned c2 = cvtpk(p[4], p[5]),   c3 = cvtpk(p[6], p[7]);
      unsigned c4 = cvtpk(p[8], p[9]),   c5 = cvtpk(p[10], p[11]);
      unsigned c6 = cvtpk(p[12], p[13]), c7 = cvtpk(p[14], p[15]);
      unsigned y0 = __shfl_xor(c0, 32, 64), y1 = __shfl_xor(c1, 32, 64);
      unsigned y2 = __shfl_xor(c2, 32, 64), y3 = __shfl_xor(c3, 32, 64);
      unsigned y4 = __shfl_xor(c4, 32, 64), y5 = __shfl_xor(c5, 32, 64);
      unsigned y6 = __shfl_xor(c6, 32, 64), y7 = __shfl_xor(c7, 32, 64);
      u32x4 f0 = { g ? y2 : c0, g ? y3 : c1, g ? c2 : y0, g ? c3 : y1 };
      u32x4 f1 = { g ? y6 : c4, g ? y7 : c5, g ? c6 : y4, g ? c7 : y5 };
      bf16x8 pb0 = __builtin_bit_cast(bf16x8, f0);
      bf16x8 pb1 = __builtin_bit_cast(bf16x8, f1);
      __builtin_amdgcn_s_setprio(1);
      ot0 = mfma32(vf[0], pb0, ot0);
      ot0 = mfma32(vf[1], pb1, ot0);
      ot1 = mfma32(vf[2], pb0, ot1);
      ot1 = mfma32(vf[3], pb1, ot1);
      __builtin_amdgcn_s_setprio(0);
#pragma unroll
      for (int ks = 0; ks < 4; ++ks) kf[ks] = kn[ks];
#pragma unroll
      for (int q = 0; q < 4; ++q) vf[q] = vn[q];
    }
  }
  // ---- split-K merge: wave 1 publishes partials, wave 0 combines ----
  if (w == 1) {
#pragma unroll
    for (int r = 0; r < 16; ++r) {
      O1f[r][l]      = ot0[r];
      O1f[16 + r][l] = ot1[r];
    }
    M1[l] = m;
    L1[l] = lden;
  }
  __syncthreads();
  if (w == 0) {
    float m1 = M1[l], l1c = L1[l];
    float mN = fmaxf(m, m1);
    float s0 = __expf(m - mN), s1 = __expf(m1 - mN);
    lden = lden * s0 + l1c * s1;
    lden += __shfl_xor(lden, 32, 64);
    float inv = 1.0f / lden;
#pragma unroll
    for (int r = 0; r < 16; ++r) {
      ot0[r] = ot0[r] * s0 + O1f[r][l] * s1;
      ot1[r] = ot1[r] * s0 + O1f[16 + r][l] * s1;
    }
#pragma unroll
    for (int r = 0; r < 16; ++r) {
      int d = (r & 3) + 8 * (r >> 2) + 4 * g;
      T[q32 * 72 + d]      = f2bf(ot0[r] * inv);
      T[q32 * 72 + 32 + d] = f2bf(ot1[r] * inv);
    }
#pragma unroll
    for (int j2 = 0; j2 < 4; ++j2) {
      int col = g * 32 + j2 * 8;
      u16x8 vv = *(const u16x8*)&T[q32 * 72 + col];
      *(u16x8*)&O[(tok0 + q0 + q32) * DM + hoff + col] = vv;
    }
  }
}

// ---------------- fused residual + LayerNorm ----------------
// MODE 0: bf16+bf16 -> bf16. MODE 1: bf16+f32 -> f32. MODE 2: bf16+bf16 -> f32.
template<int MODE>
__global__ __launch_bounds__(256) void ln_kernel(
    const unsigned short* __restrict__ Xa, const void* __restrict__ Xc,
    const float* __restrict__ g, const float* __restrict__ be,
    void* __restrict__ outp) {
  const int row = blockIdx.x, t = threadIdx.x;
  const size_t base = (size_t)row * DM + t * 4;
  float x[4];
  u16x4 a = *(const u16x4*)&Xa[base];
  if (MODE == 0 || MODE == 2) {
    u16x4 c = *(const u16x4*)&((const unsigned short*)Xc)[base];
#pragma unroll
    for (int i = 0; i < 4; ++i) x[i] = bf2f(a[i]) + bf2f(c[i]);
  } else {
    f32x4 c = *(const f32x4*)&((const float*)Xc)[base];
#pragma unroll
    for (int i = 0; i < 4; ++i) x[i] = bf2f(a[i]) + c[i];
  }
  float s = x[0] + x[1] + x[2] + x[3];
  float ss = x[0] * x[0] + x[1] * x[1] + x[2] * x[2] + x[3] * x[3];
#pragma unroll
  for (int m = 1; m < 64; m <<= 1) {
    s  += __shfl_xor(s, m, 64);
    ss += __shfl_xor(ss, m, 64);
  }
  __shared__ float red[8];
  const int w = t >> 6;
  if ((t & 63) == 0) { red[w * 2] = s; red[w * 2 + 1] = ss; }
  __syncthreads();
  s  = red[0] + red[2] + red[4] + red[6];
  ss = red[1] + red[3] + red[5] + red[7];
  const float mean = s * (1.0f / DM);
  const float var = ss * (1.0f / DM) - mean * mean;
  const float rstd = rsqrtf(var + 1e-5f);
  if (MODE == 0) {
    u16x4 o;
#pragma unroll
    for (int i = 0; i < 4; ++i) {
      int cx = t * 4 + i;
      o[i] = f2bf((x[i] - mean) * rstd * g[cx] + be[cx]);
    }
    *(u16x4*)&((unsigned short*)outp)[base] = o;
  } else {
    f32x4 o;
#pragma unroll
    for (int i = 0; i < 4; ++i) {
      int cx = t * 4 + i;
      o[i] = (x[i] - mean) * rstd * g[cx] + be[cx];
    }
    *(f32x4*)&((float*)outp)[base] = o;
  }
}

extern "C" void kernel_launch(void* const* d_in, const int* in_sizes, int n_in,
                              void* d_out, int out_size, void* d_ws, size_t ws_size,
                              hipStream_t stream) {
  (void)in_sizes; (void)n_in; (void)out_size; (void)ws_size;
  const float* kq  = (const float*)d_in[0];
  const float* v   = (const float*)d_in[1];
  const float* Wk  = (const float*)d_in[2];
  const float* bk  = (const float*)d_in[3];
  const float* Wq  = (const float*)d_in[4];
  const float* bq  = (const float*)d_in[5];
  const float* Wv  = (const float*)d_in[6];
  const float* bv  = (const float*)d_in[7];
  const float* W1  = (const float*)d_in[8];
  const float* b1  = (const float*)d_in[9];
  const float* W2  = (const float*)d_in[10];
  const float* b2  = (const float*)d_in[11];
  const float* g1  = (const float*)d_in[12];
  const float* be1 = (const float*)d_in[13];
  const float* g2  = (const float*)d_in[14];
  const float* be2 = (const float*)d_in[15];
  float* out = (float*)d_out;
  uint8_t* ws = (uint8_t*)d_ws;

  // Workspace overlay (lifetimes): region A [0, 73.4MB) holds X/Wqkv/Q/K/attn
  // which are all dead before FFN1; F1b reuses it. VIg + bqkv overlay the
  // F2b region (both dead before F2b is written by FFN2).
  unsigned short* Xb   = (unsigned short*)(ws + 0);
  unsigned short* Wkb  = (unsigned short*)(ws + 16777216);   // Wk|Wq|Wv contiguous
  unsigned short* Qb   = (unsigned short*)(ws + 23068672);
  unsigned short* Kb   = (unsigned short*)(ws + 39845888);
  unsigned short* Ab   = (unsigned short*)(ws + 56623104);
  unsigned short* F1b  = (unsigned short*)(ws + 0);          // overlay
  unsigned short* W1b  = (unsigned short*)(ws + 73400320);   // W1|W2 contiguous
  unsigned short* Vb   = (unsigned short*)(ws + 90177536);
  unsigned short* Hb   = (unsigned short*)(ws + 106954752);
  unsigned short* F2b  = (unsigned short*)(ws + 123731968);  // bf16 FFN2 out
  unsigned short* VIg  = (unsigned short*)(ws + 123731968);  // overlay, 16MB (dead before F2b)
  float*          bqkv = (float*)(ws + 140509184);           // overlay, 12KB
  unsigned short* W2b  = W1b + 4194304;

  concat_cast<<<TOK * DM / 1024, 256, 0, stream>>>(kq, v, Xb);
  castW5<<<11264, 256, 0, stream>>>(Wk, Wq, Wv, W1, W2, Wkb, W1b);
  bias3<<<12, 256, 0, stream>>>(bk, bq, bv, bqkv);

  // Fused QKV: M=8192, N=3072, K=1024. BM=128 -> grid 64x12 = 768 (3/CU).
  gemm256<128, 5><<<768, 512, 98304, stream>>>(
      Xb, Wkb, bqkv, Kb, Qb, Vb, VIg, TOK, 3072, DM, 8, 12, 1);

  // Split-K attention: one block per (bh, unit), 2 waves split the key range.
  attn_kernel<<<dim3(64, 64), 128, 0, stream>>>(Qb, Kb, VIg, Ab);

  ln_kernel<0><<<TOK, 256, 0, stream>>>(Vb, Ab, g1, be1, Hb);

  // FFN1: 256x256 -> grid 32x16 = 512, XCD patch PR=8, PC=8, NPC=2. 128 KiB.
  gemm256<256, 2><<<512, 512, 131072, stream>>>(
      Hb, W1b, b1, F1b, nullptr, nullptr, nullptr, TOK, FFD, DM, 8, 8, 2);
  // FFN2: BM=128 -> grid 64x4 = 256 (full chip), PR=8, PC=4, NPC=1. 96 KiB.
  // bf16 output (EPI=1): halves FFN2 store + LN re-read traffic.
  gemm256<128, 1><<<256, 512, 98304, stream>>>(
      F1b, W2b, b2, F2b, nullptr, nullptr, nullptr, TOK, DM, FFD, 8, 4, 1);

  ln_kernel<2><<<TOK, 256, 0, stream>>>(Hb, F2b, g2, be2, out);
}

// Round 19
// 359.121 us; speedup vs baseline: 2.7029x; 2.7029x over previous
//
#include <hip/hip_runtime.h>
#include <stdint.h>

#define SEQ 2048
#define DM  1024
#define NH  16
#define HD  64
#define FFD 4096
#define TOK 8192

typedef __bf16 bf16x8 __attribute__((ext_vector_type(8)));
typedef float  f32x4  __attribute__((ext_vector_type(4)));
typedef float  f32x16 __attribute__((ext_vector_type(16)));
typedef unsigned short u16x8 __attribute__((ext_vector_type(8)));
typedef unsigned short u16x4 __attribute__((ext_vector_type(4)));
typedef unsigned int   u32x4 __attribute__((ext_vector_type(4)));

__device__ __forceinline__ unsigned short f2bf(float f) {
  unsigned u = __builtin_bit_cast(unsigned, f);
  u += 0x7fffu + ((u >> 16) & 1u);
  return (unsigned short)(u >> 16);
}
__device__ __forceinline__ float bf2f(unsigned short h) {
  return __builtin_bit_cast(float, ((unsigned)h) << 16);
}
__device__ __forceinline__ f32x4 mfma16(bf16x8 a, bf16x8 b, f32x4 c) {
  return __builtin_amdgcn_mfma_f32_16x16x32_bf16(a, b, c, 0, 0, 0);
}
__device__ __forceinline__ f32x16 mfma32(bf16x8 a, bf16x8 b, f32x16 c) {
  return __builtin_amdgcn_mfma_f32_32x32x16_bf16(a, b, c, 0, 0, 0);
}
__device__ __forceinline__ unsigned cvtpk(float lo, float hi) {
  unsigned r;
  asm("v_cvt_pk_bf16_f32 %0, %1, %2" : "=v"(r) : "v"(lo), "v"(hi));
  return r;
}
__device__ __forceinline__ void gld_lds16(void* lds, const void* g) {
  __builtin_amdgcn_global_load_lds((__attribute__((address_space(1))) void*)g,
                                   (__attribute__((address_space(3))) void*)lds,
                                   16, 0, 0);
}

// ---------------- elementwise casts ----------------
__global__ __launch_bounds__(256) void concat_cast(
    const float* __restrict__ kq, const float* __restrict__ v,
    unsigned short* __restrict__ X) {
  int i = (blockIdx.x * 256 + threadIdx.x) * 4;   // over TOK*DM
  int tkn = i >> 10;
  int c = i & 1023;
  const float* s = (c < 512) ? (kq + (size_t)tkn * 512 + c)
                             : (v  + (size_t)tkn * 512 + (c - 512));
  f32x4 f = *(const f32x4*)s;
  u16x4 o = { f2bf(f[0]), f2bf(f[1]), f2bf(f[2]), f2bf(f[3]) };
  *(u16x4*)&X[i] = o;
}

// All 5 weight casts in ONE kernel. dst1 = Wk|Wq|Wv contiguous (3M elems),
// dst2 = W1|W2 contiguous (8M elems). Segment branch is wave-uniform.
__global__ __launch_bounds__(256) void castW5(
    const float* __restrict__ Wk, const float* __restrict__ Wq,
    const float* __restrict__ Wv, const float* __restrict__ W1,
    const float* __restrict__ W2, unsigned short* __restrict__ dst1,
    unsigned short* __restrict__ dst2) {
  int e = (blockIdx.x * 256 + threadIdx.x) * 4;   // over 11,534,336 elems
  const float* src;
  unsigned short* dst;
  if (e < 3145728) {
    src = (e < 1048576) ? (Wk + e)
        : (e < 2097152) ? (Wq + (e - 1048576))
                        : (Wv + (e - 2097152));
    dst = dst1 + e;
  } else {
    int e2 = e - 3145728;
    src = (e2 < 4194304) ? (W1 + e2) : (W2 + (e2 - 4194304));
    dst = dst2 + e2;
  }
  f32x4 f = *(const f32x4*)src;
  u16x4 o = { f2bf(f[0]), f2bf(f[1]), f2bf(f[2]), f2bf(f[3]) };
  *(u16x4*)dst = o;
}

__global__ __launch_bounds__(256) void bias3(
    const float* __restrict__ a, const float* __restrict__ b,
    const float* __restrict__ c, float* __restrict__ o) {
  int i = blockIdx.x * 256 + threadIdx.x;
  if (i < 1024) o[i] = a[i];
  else if (i < 2048) o[i] = b[i - 1024];
  else if (i < 3072) o[i] = c[i - 2048];
}

// ---------------- counted-pipeline GEMM (R10/R15-verified) ------------------
// BM x 256 tile, BK=64, 512 threads (8 waves 2M x 4N). Double-buffered LDS.
// Per K-tile: vmcnt(0); s_barrier; stage(t+1) into other buffer; ds_read+MFMA.
// T2 XOR swizzle -> bank-conflict 0. XCD 2D-patch mapping -> FETCH ~2x unique.
// EPI: 0 f32 | 1 bf16 | 2 exact-GELU bf16 | 5 fused-QKV.
template<int BM, int EPI>
__global__ __launch_bounds__(512, 2) void gemm256(
    const unsigned short* __restrict__ A, const unsigned short* __restrict__ B,
    const float* __restrict__ bias, void* __restrict__ Cout,
    void* __restrict__ CoutQ, void* __restrict__ CoutV, void* __restrict__ CoutVI,
    int M, int N, int K, int PR, int PC, int NPC) {
  constexpr int MF = BM / 32;       // per-wave M frags (8 | 4)
  constexpr int MG = MF / 4;        // MFMA groups (2 | 1)
  extern __shared__ __align__(16) unsigned short lds[];
  unsigned short* Asm0 = lds;                     // [2][BM*64]
  unsigned short* Bsm0 = lds + 2 * BM * 64;       // [2][256*64]
  const int tid = threadIdx.x;
  const int w = tid >> 6, l = tid & 63, lr = l & 15, lg = l >> 4;
  const int wm = w >> 2, wn = w & 3;
  const int bid = blockIdx.x;
  const int xcd = bid & 7;
  const int i = bid >> 3;
  const int patch_r = xcd / NPC, patch_c = xcd % NPC;
  const int bm = (patch_r * PR + (i % PR)) * BM;
  const int bn = (patch_c * PC + (i / PR)) * 256;
  const int NT = K >> 6;
  const int srow = tid >> 3;
  const int sc8  = tid & 7;

  f32x4 acc[MF][4] = {};

  auto stage = [&](int kt, int bb) {
    unsigned short* da = Asm0 + bb * (BM * 64);
    unsigned short* db = Bsm0 + bb * (256 * 64);
#pragma unroll
    for (int p = 0; p < BM / 64; ++p) {
      int row = p * 64 + srow;
      gld_lds16(da + (p * 512 + w * 64) * 8,
                &A[(size_t)(bm + row) * K + kt * 64 + ((sc8 ^ (row & 7)) << 3)]);
    }
#pragma unroll
    for (int p = 0; p < 4; ++p) {
      int row = p * 64 + srow;
      gld_lds16(db + (p * 512 + w * 64) * 8,
                &B[(size_t)(bn + row) * K + kt * 64 + ((sc8 ^ (row & 7)) << 3)]);
    }
  };

  stage(0, 0);

  for (int t = 0; t < NT; ++t) {
    asm volatile("s_waitcnt vmcnt(0)" ::: "memory");   // stage(t) complete
    __builtin_amdgcn_s_barrier();                      // all waves' stage(t) done
    if (t + 1 < NT) stage(t + 1, (t + 1) & 1);         // full-tile lead
    const unsigned short* As = Asm0 + (t & 1) * (BM * 64);
    const unsigned short* Bs = Bsm0 + (t & 1) * (256 * 64);
    bf16x8 bv[4][2];
#pragma unroll
    for (int fn = 0; fn < 4; ++fn)
#pragma unroll
      for (int kk = 0; kk < 2; ++kk) {
        int row = wn * 64 + fn * 16 + lr;
        int c8 = (kk * 4 + lg) ^ (row & 7);
        bv[fn][kk] = *(const bf16x8*)&Bs[row * 64 + c8 * 8];
      }
#pragma unroll
    for (int mg = 0; mg < MG; ++mg) {
      bf16x8 av[4][2];
#pragma unroll
      for (int fr = 0; fr < 4; ++fr)
#pragma unroll
        for (int kk = 0; kk < 2; ++kk) {
          int row = wm * (BM / 2) + (mg * 4 + fr) * 16 + lr;
          int c8 = (kk * 4 + lg) ^ (row & 7);
          av[fr][kk] = *(const bf16x8*)&As[row * 64 + c8 * 8];
        }
      __builtin_amdgcn_s_setprio(1);
#pragma unroll
      for (int fr = 0; fr < 4; ++fr)
#pragma unroll
        for (int nf = 0; nf < 4; ++nf)
#pragma unroll
          for (int kk = 0; kk < 2; ++kk)
            acc[mg * 4 + fr][nf] = mfma16(av[fr][kk], bv[nf][kk], acc[mg * 4 + fr][nf]);
      __builtin_amdgcn_s_setprio(0);
    }
  }
  // ---- epilogue ----
#pragma unroll
  for (int mf = 0; mf < MF; ++mf) {
    int row0 = bm + wm * (BM / 2) + mf * 16 + lg * 4;
#pragma unroll
    for (int nf = 0; nf < 4; ++nf) {
      int col = bn + wn * 64 + nf * 16 + lr;
      float bcol = bias[col];
#pragma unroll
      for (int r = 0; r < 4; ++r) {
        float vv = acc[mf][nf][r] + bcol;
        int row = row0 + r;
        if (EPI == 2) vv = 0.5f * vv * (1.0f + erff(vv * 0.70710678118654752f));
        if (EPI == 0) {
          ((float*)Cout)[(size_t)row * N + col] = vv;
        } else if (EPI == 5) {
          int third = col >> 10, c = col & 1023;
          unsigned short hv = f2bf(vv);
          int bb = row >> 11, tt = row & 2047;
          if (third == 0) {          // K -> KI[bh][dc16][tok][16]
            int hh = c >> 6, dc = (c >> 4) & 3, dl = c & 15;
            ((unsigned short*)Cout)[((((size_t)(bb * 16 + hh) * 4 + dc) * 2048 + tt) << 4) + dl] = hv;
          } else if (third == 1) {   // Q rows
            ((unsigned short*)CoutQ)[(size_t)row * 1024 + c] = hv;
          } else {                   // V rows + VI[bh][kt16][d][16]
            ((unsigned short*)CoutV)[(size_t)row * 1024 + c] = hv;
            int hh = c >> 6, d = c & 63;
            ((unsigned short*)CoutVI)[((((size_t)(bb * 16 + hh) * 128 + (tt >> 4)) * 64 + d) << 4) + (tt & 15)] = hv;
          }
        } else {
          ((unsigned short*)Cout)[(size_t)row * N + col] = f2bf(vv);
        }
      }
    }
  }
}

// ---------------- causal flash attention, split-K two-wave merge ------------
// R16-verified form, launch_bounds (128,4): live state ~90 VGPR needs the
// 128-reg budget (R18's (128,6) forced VGPR=40 -> TB-scale spill; twice-
// confirmed lesson: derive occupancy bounds from live-state arithmetic).
__global__ __launch_bounds__(128, 4) void attn_kernel(
    const unsigned short* __restrict__ Q, const unsigned short* __restrict__ KI,
    const unsigned short* __restrict__ VI, unsigned short* __restrict__ O) {
  __shared__ __align__(16) unsigned short T[32 * 72];
  __shared__ __align__(16) float O1f[32][68];
  __shared__ float M1[64], L1[64];
  const int tid = threadIdx.x;
  const int w = tid >> 6, l = tid & 63;
  const int q32 = l & 31;
  const int g = l >> 5;
  const int x = blockIdx.x;
  const int bh = (x & 7) * 8 + (x >> 3);    // XCD-cluster same-head blocks
  const int b = bh >> 4, h = bh & 15;
  const int u = 63 - (int)blockIdx.y;       // heavy units first
  const int nt = u + 1;
  const int nh = (nt + 1) >> 1;             // wave 0 tile count
  const int jbeg = w ? nh : 0;
  const int jend = w ? nt : nh;
  const size_t tok0 = (size_t)b * SEQ;
  const size_t hoff = (size_t)h * 64;
  const unsigned short* Kp = KI + (size_t)bh * 4 * SEQ * 16;
  const unsigned short* Vp = VI + (size_t)bh * 128 * 64 * 16;

  const int q0 = u * 32;
  const int qg = q0 + q32;            // this lane's q row

  bf16x8 qf[4];
#pragma unroll
  for (int ks = 0; ks < 4; ++ks)
    qf[ks] = *(const bf16x8*)&Q[(tok0 + qg) * DM + hoff + ks * 16 + g * 8];

  f32x16 ot0 = {}, ot1 = {};
  float m = -3.0e38f, lden = 0.f;

  if (jbeg < jend) {
    bf16x8 kf[4], vf[4];
#pragma unroll
    for (int ks = 0; ks < 4; ++ks)
      kf[ks] = *(const bf16x8*)&Kp[((size_t)ks * SEQ + jbeg * 32 + q32) * 16 + g * 8];
#pragma unroll
    for (int dt = 0; dt < 2; ++dt)
#pragma unroll
      for (int s = 0; s < 2; ++s)
        vf[dt * 2 + s] = *(const bf16x8*)&Vp[(((size_t)jbeg * 2 + s) * 64 + dt * 32 + q32) * 16 + g * 8];

#pragma unroll 1
    for (int j = jbeg; j < jend; ++j) {
      f32x16 st = {};
      __builtin_amdgcn_s_setprio(1);
#pragma unroll
      for (int ks = 0; ks < 4; ++ks) st = mfma32(kf[ks], qf[ks], st);
      __builtin_amdgcn_s_setprio(0);
      const int jn = (j + 1 < jend) ? j + 1 : j;
      bf16x8 kn[4], vn[4];
#pragma unroll
      for (int ks = 0; ks < 4; ++ks)
        kn[ks] = *(const bf16x8*)&Kp[((size_t)ks * SEQ + jn * 32 + q32) * 16 + g * 8];
#pragma unroll
      for (int dt = 0; dt < 2; ++dt)
#pragma unroll
        for (int s = 0; s < 2; ++s)
          vn[dt * 2 + s] = *(const bf16x8*)&Vp[(((size_t)jn * 2 + s) * 64 + dt * 32 + q32) * 16 + g * 8];
      if (j == u) {
#pragma unroll
        for (int r = 0; r < 16; ++r) {
          int kg = j * 32 + (r & 3) + 8 * (r >> 2) + 4 * g;
          if (kg > qg) st[r] = -3.0e38f;
        }
      }
      float x0 = fmaxf(st[0], st[1]),  x1 = fmaxf(st[2], st[3]);
      float x2 = fmaxf(st[4], st[5]),  x3 = fmaxf(st[6], st[7]);
      float x4 = fmaxf(st[8], st[9]),  x5 = fmaxf(st[10], st[11]);
      float x6 = fmaxf(st[12], st[13]), x7 = fmaxf(st[14], st[15]);
      x0 = fmaxf(x0, x1); x2 = fmaxf(x2, x3); x4 = fmaxf(x4, x5); x6 = fmaxf(x6, x7);
      x0 = fmaxf(x0, x2); x4 = fmaxf(x4, x6);
      float pmax = fmaxf(x0, x4);
      if (__any(pmax - m > 8.0f)) {
        float pp = fmaxf(pmax, __shfl_xor(pmax, 32, 64));
        float mnew = fmaxf(m, pp);
        float sc = __expf(m - mnew);
#pragma unroll
        for (int r = 0; r < 16; ++r) { ot0[r] *= sc; ot1[r] *= sc; }
        lden *= sc;
        m = mnew;
      }
      float p[16];
#pragma unroll
      for (int r = 0; r < 16; ++r) p[r] = __expf(st[r] - m);
      {
        float s0 = p[0] + p[1], s1 = p[2] + p[3], s2 = p[4] + p[5], s3 = p[6] + p[7];
        float s4 = p[8] + p[9], s5 = p[10] + p[11], s6 = p[12] + p[13], s7 = p[14] + p[15];
        s0 += s1; s2 += s3; s4 += s5; s6 += s7;
        s0 += s2; s4 += s6;
        lden += s0 + s4;
      }
      unsigned c0 = cvtpk(p[0], p[1]),   c1 = cvtpk(p[2], p[3]);
      unsigned c2 = cvtpk(p[4], p[5]),   c3 = cvtpk(p[6], p[7]);
      unsigned c4 = cvtpk(p[8], p[9]),   c5 = cvtpk(p[10], p[11]);
      unsigned c6 = cvtpk(p[12], p[13]), c7 = cvtpk(p[14], p[15]);
      unsigned y0 = __shfl_xor(c0, 32, 64), y1 = __shfl_xor(c1, 32, 64);
      unsigned y2 = __shfl_xor(c2, 32, 64), y3 = __shfl_xor(c3, 32, 64);
      unsigned y4 = __shfl_xor(c4, 32, 64), y5 = __shfl_xor(c5, 32, 64);
      unsigned y6 = __shfl_xor(c6, 32, 64), y7 = __shfl_xor(c7, 32, 64);
      u32x4 f0 = { g ? y2 : c0, g ? y3 : c1, g ? c2 : y0, g ? c3 : y1 };
      u32x4 f1 = { g ? y6 : c4, g ? y7 : c5, g ? c6 : y4, g ? c7 : y5 };
      bf16x8 pb0 = __builtin_bit_cast(bf16x8, f0);
      bf16x8 pb1 = __builtin_bit_cast(bf16x8, f1);
      __builtin_amdgcn_s_setprio(1);
      ot0 = mfma32(vf[0], pb0, ot0);
      ot0 = mfma32(vf[1], pb1, ot0);
      ot1 = mfma32(vf[2], pb0, ot1);
      ot1 = mfma32(vf[3], pb1, ot1);
      __builtin_amdgcn_s_setprio(0);
#pragma unroll
      for (int ks = 0; ks < 4; ++ks) kf[ks] = kn[ks];
#pragma unroll
      for (int q = 0; q < 4; ++q) vf[q] = vn[q];
    }
  }
  // ---- split-K merge: wave 1 publishes partials, wave 0 combines ----
  if (w == 1) {
#pragma unroll
    for (int r = 0; r < 16; ++r) {
      O1f[r][l]      = ot0[r];
      O1f[16 + r][l] = ot1[r];
    }
    M1[l] = m;
    L1[l] = lden;
  }
  __syncthreads();
  if (w == 0) {
    float m1 = M1[l], l1c = L1[l];
    float mN = fmaxf(m, m1);
    float s0 = __expf(m - mN), s1 = __expf(m1 - mN);
    lden = lden * s0 + l1c * s1;
    lden += __shfl_xor(lden, 32, 64);
    float inv = 1.0f / lden;
#pragma unroll
    for (int r = 0; r < 16; ++r) {
      ot0[r] = ot0[r] * s0 + O1f[r][l] * s1;
      ot1[r] = ot1[r] * s0 + O1f[16 + r][l] * s1;
    }
#pragma unroll
    for (int r = 0; r < 16; ++r) {
      int d = (r & 3) + 8 * (r >> 2) + 4 * g;
      T[q32 * 72 + d]      = f2bf(ot0[r] * inv);
      T[q32 * 72 + 32 + d] = f2bf(ot1[r] * inv);
    }
#pragma unroll
    for (int j2 = 0; j2 < 4; ++j2) {
      int col = g * 32 + j2 * 8;
      u16x8 vv = *(const u16x8*)&T[q32 * 72 + col];
      *(u16x8*)&O[(tok0 + q0 + q32) * DM + hoff + col] = vv;
    }
  }
}

// ---------------- fused residual + LayerNorm ----------------
// MODE 0: bf16+bf16 -> bf16. MODE 1: bf16+f32 -> f32. MODE 2: bf16+bf16 -> f32.
template<int MODE>
__global__ __launch_bounds__(256) void ln_kernel(
    const unsigned short* __restrict__ Xa, const void* __restrict__ Xc,
    const float* __restrict__ g, const float* __restrict__ be,
    void* __restrict__ outp) {
  const int row = blockIdx.x, t = threadIdx.x;
  const size_t base = (size_t)row * DM + t * 4;
  float x[4];
  u16x4 a = *(const u16x4*)&Xa[base];
  if (MODE == 0 || MODE == 2) {
    u16x4 c = *(const u16x4*)&((const unsigned short*)Xc)[base];
#pragma unroll
    for (int i = 0; i < 4; ++i) x[i] = bf2f(a[i]) + bf2f(c[i]);
  } else {
    f32x4 c = *(const f32x4*)&((const float*)Xc)[base];
#pragma unroll
    for (int i = 0; i < 4; ++i) x[i] = bf2f(a[i]) + c[i];
  }
  float s = x[0] + x[1] + x[2] + x[3];
  float ss = x[0] * x[0] + x[1] * x[1] + x[2] * x[2] + x[3] * x[3];
#pragma unroll
  for (int m = 1; m < 64; m <<= 1) {
    s  += __shfl_xor(s, m, 64);
    ss += __shfl_xor(ss, m, 64);
  }
  __shared__ float red[8];
  const int w = t >> 6;
  if ((t & 63) == 0) { red[w * 2] = s; red[w * 2 + 1] = ss; }
  __syncthreads();
  s  = red[0] + red[2] + red[4] + red[6];
  ss = red[1] + red[3] + red[5] + red[7];
  const float mean = s * (1.0f / DM);
  const float var = ss * (1.0f / DM) - mean * mean;
  const float rstd = rsqrtf(var + 1e-5f);
  if (MODE == 0) {
    u16x4 o;
#pragma unroll
    for (int i = 0; i < 4; ++i) {
      int cx = t * 4 + i;
      o[i] = f2bf((x[i] - mean) * rstd * g[cx] + be[cx]);
    }
    *(u16x4*)&((unsigned short*)outp)[base] = o;
  } else {
    f32x4 o;
#pragma unroll
    for (int i = 0; i < 4; ++i) {
      int cx = t * 4 + i;
      o[i] = (x[i] - mean) * rstd * g[cx] + be[cx];
    }
    *(f32x4*)&((float*)outp)[base] = o;
  }
}

extern "C" void kernel_launch(void* const* d_in, const int* in_sizes, int n_in,
                              void* d_out, int out_size, void* d_ws, size_t ws_size,
                              hipStream_t stream) {
  (void)in_sizes; (void)n_in; (void)out_size; (void)ws_size;
  const float* kq  = (const float*)d_in[0];
  const float* v   = (const float*)d_in[1];
  const float* Wk  = (const float*)d_in[2];
  const float* bk  = (const float*)d_in[3];
  const float* Wq  = (const float*)d_in[4];
  const float* bq  = (const float*)d_in[5];
  const float* Wv  = (const float*)d_in[6];
  const float* bv  = (const float*)d_in[7];
  const float* W1  = (const float*)d_in[8];
  const float* b1  = (const float*)d_in[9];
  const float* W2  = (const float*)d_in[10];
  const float* b2  = (const float*)d_in[11];
  const float* g1  = (const float*)d_in[12];
  const float* be1 = (const float*)d_in[13];
  const float* g2  = (const float*)d_in[14];
  const float* be2 = (const float*)d_in[15];
  float* out = (float*)d_out;
  uint8_t* ws = (uint8_t*)d_ws;

  // Workspace overlay (lifetimes): region A [0, 73.4MB) holds X/Wqkv/Q/K/attn
  // which are all dead before FFN1; F1b reuses it. VIg + bqkv overlay the
  // F2b region (both dead before F2b is written by FFN2).
  unsigned short* Xb   = (unsigned short*)(ws + 0);
  unsigned short* Wkb  = (unsigned short*)(ws + 16777216);   // Wk|Wq|Wv contiguous
  unsigned short* Qb   = (unsigned short*)(ws + 23068672);
  unsigned short* Kb   = (unsigned short*)(ws + 39845888);
  unsigned short* Ab   = (unsigned short*)(ws + 56623104);
  unsigned short* F1b  = (unsigned short*)(ws + 0);          // overlay
  unsigned short* W1b  = (unsigned short*)(ws + 73400320);   // W1|W2 contiguous
  unsigned short* Vb   = (unsigned short*)(ws + 90177536);
  unsigned short* Hb   = (unsigned short*)(ws + 106954752);
  unsigned short* F2b  = (unsigned short*)(ws + 123731968);  // bf16 FFN2 out
  unsigned short* VIg  = (unsigned short*)(ws + 123731968);  // overlay (dead before F2b)
  float*          bqkv = (float*)(ws + 140509184);           // overlay, 12KB
  unsigned short* W2b  = W1b + 4194304;

  concat_cast<<<TOK * DM / 1024, 256, 0, stream>>>(kq, v, Xb);
  castW5<<<11264, 256, 0, stream>>>(Wk, Wq, Wv, W1, W2, Wkb, W1b);
  bias3<<<12, 256, 0, stream>>>(bk, bq, bv, bqkv);

  // Fused QKV: M=8192, N=3072, K=1024. BM=128 -> grid 64x12 = 768 (3/CU).
  gemm256<128, 5><<<768, 512, 98304, stream>>>(
      Xb, Wkb, bqkv, Kb, Qb, Vb, VIg, TOK, 3072, DM, 8, 12, 1);

  // Split-K attention: one block per (bh, unit), 2 waves split the key range.
  attn_kernel<<<dim3(64, 64), 128, 0, stream>>>(Qb, Kb, VIg, Ab);

  ln_kernel<0><<<TOK, 256, 0, stream>>>(Vb, Ab, g1, be1, Hb);

  // FFN1: 256x256 -> grid 32x16 = 512, XCD patch PR=8, PC=8, NPC=2. 128 KiB.
  gemm256<256, 2><<<512, 512, 131072, stream>>>(
      Hb, W1b, b1, F1b, nullptr, nullptr, nullptr, TOK, FFD, DM, 8, 8, 2);
  // FFN2: BM=128 -> grid 64x4 = 256 (full chip), PR=8, PC=4, NPC=1. 96 KiB.
  // bf16 output (EPI=1): halves FFN2 store + LN re-read traffic.
  gemm256<128, 1><<<256, 512, 98304, stream>>>(
      F1b, W2b, b2, F2b, nullptr, nullptr, nullptr, TOK, DM, FFD, 8, 4, 1);

  ln_kernel<2><<<TOK, 256, 0, stream>>>(Hb, F2b, g2, be2, out);
}

// Round 20
// 357.986 us; speedup vs baseline: 2.7114x; 1.0032x over previous
//
#include <hip/hip_runtime.h>
#include <stdint.h>

#define SEQ 2048
#define DM  1024
#define NH  16
#define HD  64
#define FFD 4096
#define TOK 8192

typedef __bf16 bf16x8 __attribute__((ext_vector_type(8)));
typedef float  f32x4  __attribute__((ext_vector_type(4)));
typedef float  f32x16 __attribute__((ext_vector_type(16)));
typedef unsigned short u16x8 __attribute__((ext_vector_type(8)));
typedef unsigned short u16x4 __attribute__((ext_vector_type(4)));
typedef unsigned int   u32x4 __attribute__((ext_vector_type(4)));

__device__ __forceinline__ unsigned short f2bf(float f) {
  unsigned u = __builtin_bit_cast(unsigned, f);
  u += 0x7fffu + ((u >> 16) & 1u);
  return (unsigned short)(u >> 16);
}
__device__ __forceinline__ float bf2f(unsigned short h) {
  return __builtin_bit_cast(float, ((unsigned)h) << 16);
}
__device__ __forceinline__ f32x4 mfma16(bf16x8 a, bf16x8 b, f32x4 c) {
  return __builtin_amdgcn_mfma_f32_16x16x32_bf16(a, b, c, 0, 0, 0);
}
__device__ __forceinline__ f32x16 mfma32(bf16x8 a, bf16x8 b, f32x16 c) {
  return __builtin_amdgcn_mfma_f32_32x32x16_bf16(a, b, c, 0, 0, 0);
}
__device__ __forceinline__ unsigned cvtpk(float lo, float hi) {
  unsigned r;
  asm("v_cvt_pk_bf16_f32 %0, %1, %2" : "=v"(r) : "v"(lo), "v"(hi));
  return r;
}
__device__ __forceinline__ void gld_lds16(void* lds, const void* g) {
  __builtin_amdgcn_global_load_lds((__attribute__((address_space(1))) void*)g,
                                   (__attribute__((address_space(3))) void*)lds,
                                   16, 0, 0);
}

// ---------------- fused prologue: X concat-cast + 5 weight casts + bias3 ----
// One kernel over the combined flat element space:
//   [0, 8.39M)      : X = concat(kq, v) rows -> bf16 Xb
//   [8.39M, 19.92M) : Wk|Wq|Wv -> Wkb (3M), W1|W2 -> W1b (8M)
//   tail            : bqkv = bk|bq|bv (3072 f32, last blocks)
// All segment boundaries are multiples of the 4-elem thread granularity ->
// wave-uniform branches. Identical per-element math to R19's three kernels.
#define XN   (TOK * DM)            // 8388608
#define WQN  (DM * DM)             // 1048576
#define W3N  (3 * WQN)             // 3145728
#define W1N  (FFD * DM)            // 4194304
#define WALL (W3N + 2 * W1N)       // 11534336
#define TOTE (XN + WALL)           // 19922944

__global__ __launch_bounds__(256) void prologue(
    const float* __restrict__ kq, const float* __restrict__ v,
    const float* __restrict__ Wk, const float* __restrict__ Wq,
    const float* __restrict__ Wv, const float* __restrict__ W1,
    const float* __restrict__ W2, const float* __restrict__ bk,
    const float* __restrict__ bq, const float* __restrict__ bv,
    unsigned short* __restrict__ X, unsigned short* __restrict__ dst1,
    unsigned short* __restrict__ dst2, float* __restrict__ bqkv) {
  int e = (blockIdx.x * 256 + threadIdx.x) * 4;
  if (e < XN) {                    // X concat
    int tkn = e >> 10, c = e & 1023;
    const float* s = (c < 512) ? (kq + (size_t)tkn * 512 + c)
                               : (v  + (size_t)tkn * 512 + (c - 512));
    f32x4 f = *(const f32x4*)s;
    u16x4 o = { f2bf(f[0]), f2bf(f[1]), f2bf(f[2]), f2bf(f[3]) };
    *(u16x4*)&X[e] = o;
    return;
  }
  int e1 = e - XN;
  if (e1 < WALL) {                 // weights
    const float* src;
    unsigned short* dst;
    if (e1 < W3N) {
      src = (e1 < WQN) ? (Wk + e1)
          : (e1 < 2 * WQN) ? (Wq + (e1 - WQN))
                           : (Wv + (e1 - 2 * WQN));
      dst = dst1 + e1;
    } else {
      int e2 = e1 - W3N;
      src = (e2 < W1N) ? (W1 + e2) : (W2 + (e2 - W1N));
      dst = dst2 + e2;
    }
    f32x4 f = *(const f32x4*)src;
    u16x4 o = { f2bf(f[0]), f2bf(f[1]), f2bf(f[2]), f2bf(f[3]) };
    *(u16x4*)dst = o;
    return;
  }
  int e3 = e1 - WALL;              // bias tail: 3072 f32, 4 per thread
  if (e3 < 3072) {
#pragma unroll
    for (int i = 0; i < 4; ++i) {
      int c = e3 + i;
      bqkv[c] = (c < 1024) ? bk[c] : (c < 2048) ? bq[c - 1024] : bv[c - 2048];
    }
  }
}

// ---------------- counted-pipeline GEMM (R10/R15-verified) ------------------
// BM x 256 tile, BK=64, 512 threads (8 waves 2M x 4N). Double-buffered LDS.
// Per K-tile: vmcnt(0); s_barrier; stage(t+1) into other buffer; ds_read+MFMA.
// T2 XOR swizzle -> bank-conflict 0. XCD 2D-patch mapping -> FETCH ~2x unique.
// EPI: 0 f32 | 1 bf16 | 2 exact-GELU bf16 | 5 fused-QKV.
template<int BM, int EPI>
__global__ __launch_bounds__(512, 2) void gemm256(
    const unsigned short* __restrict__ A, const unsigned short* __restrict__ B,
    const float* __restrict__ bias, void* __restrict__ Cout,
    void* __restrict__ CoutQ, void* __restrict__ CoutV, void* __restrict__ CoutVI,
    int M, int N, int K, int PR, int PC, int NPC) {
  constexpr int MF = BM / 32;       // per-wave M frags (8 | 4)
  constexpr int MG = MF / 4;        // MFMA groups (2 | 1)
  extern __shared__ __align__(16) unsigned short lds[];
  unsigned short* Asm0 = lds;                     // [2][BM*64]
  unsigned short* Bsm0 = lds + 2 * BM * 64;       // [2][256*64]
  const int tid = threadIdx.x;
  const int w = tid >> 6, l = tid & 63, lr = l & 15, lg = l >> 4;
  const int wm = w >> 2, wn = w & 3;
  const int bid = blockIdx.x;
  const int xcd = bid & 7;
  const int i = bid >> 3;
  const int patch_r = xcd / NPC, patch_c = xcd % NPC;
  const int bm = (patch_r * PR + (i % PR)) * BM;
  const int bn = (patch_c * PC + (i / PR)) * 256;
  const int NT = K >> 6;
  const int srow = tid >> 3;
  const int sc8  = tid & 7;

  f32x4 acc[MF][4] = {};

  auto stage = [&](int kt, int bb) {
    unsigned short* da = Asm0 + bb * (BM * 64);
    unsigned short* db = Bsm0 + bb * (256 * 64);
#pragma unroll
    for (int p = 0; p < BM / 64; ++p) {
      int row = p * 64 + srow;
      gld_lds16(da + (p * 512 + w * 64) * 8,
                &A[(size_t)(bm + row) * K + kt * 64 + ((sc8 ^ (row & 7)) << 3)]);
    }
#pragma unroll
    for (int p = 0; p < 4; ++p) {
      int row = p * 64 + srow;
      gld_lds16(db + (p * 512 + w * 64) * 8,
                &B[(size_t)(bn + row) * K + kt * 64 + ((sc8 ^ (row & 7)) << 3)]);
    }
  };

  stage(0, 0);

  for (int t = 0; t < NT; ++t) {
    asm volatile("s_waitcnt vmcnt(0)" ::: "memory");   // stage(t) complete
    __builtin_amdgcn_s_barrier();                      // all waves' stage(t) done
    if (t + 1 < NT) stage(t + 1, (t + 1) & 1);         // full-tile lead
    const unsigned short* As = Asm0 + (t & 1) * (BM * 64);
    const unsigned short* Bs = Bsm0 + (t & 1) * (256 * 64);
    bf16x8 bv[4][2];
#pragma unroll
    for (int fn = 0; fn < 4; ++fn)
#pragma unroll
      for (int kk = 0; kk < 2; ++kk) {
        int row = wn * 64 + fn * 16 + lr;
        int c8 = (kk * 4 + lg) ^ (row & 7);
        bv[fn][kk] = *(const bf16x8*)&Bs[row * 64 + c8 * 8];
      }
#pragma unroll
    for (int mg = 0; mg < MG; ++mg) {
      bf16x8 av[4][2];
#pragma unroll
      for (int fr = 0; fr < 4; ++fr)
#pragma unroll
        for (int kk = 0; kk < 2; ++kk) {
          int row = wm * (BM / 2) + (mg * 4 + fr) * 16 + lr;
          int c8 = (kk * 4 + lg) ^ (row & 7);
          av[fr][kk] = *(const bf16x8*)&As[row * 64 + c8 * 8];
        }
      __builtin_amdgcn_s_setprio(1);
#pragma unroll
      for (int fr = 0; fr < 4; ++fr)
#pragma unroll
        for (int nf = 0; nf < 4; ++nf)
#pragma unroll
          for (int kk = 0; kk < 2; ++kk)
            acc[mg * 4 + fr][nf] = mfma16(av[fr][kk], bv[nf][kk], acc[mg * 4 + fr][nf]);
      __builtin_amdgcn_s_setprio(0);
    }
  }
  // ---- epilogue ----
#pragma unroll
  for (int mf = 0; mf < MF; ++mf) {
    int row0 = bm + wm * (BM / 2) + mf * 16 + lg * 4;
#pragma unroll
    for (int nf = 0; nf < 4; ++nf) {
      int col = bn + wn * 64 + nf * 16 + lr;
      float bcol = bias[col];
#pragma unroll
      for (int r = 0; r < 4; ++r) {
        float vv = acc[mf][nf][r] + bcol;
        int row = row0 + r;
        if (EPI == 2) vv = 0.5f * vv * (1.0f + erff(vv * 0.70710678118654752f));
        if (EPI == 0) {
          ((float*)Cout)[(size_t)row * N + col] = vv;
        } else if (EPI == 5) {
          int third = col >> 10, c = col & 1023;
          unsigned short hv = f2bf(vv);
          int bb = row >> 11, tt = row & 2047;
          if (third == 0) {          // K -> KI[bh][dc16][tok][16]
            int hh = c >> 6, dc = (c >> 4) & 3, dl = c & 15;
            ((unsigned short*)Cout)[((((size_t)(bb * 16 + hh) * 4 + dc) * 2048 + tt) << 4) + dl] = hv;
          } else if (third == 1) {   // Q rows
            ((unsigned short*)CoutQ)[(size_t)row * 1024 + c] = hv;
          } else {                   // V rows + VI[bh][kt16][d][16]
            ((unsigned short*)CoutV)[(size_t)row * 1024 + c] = hv;
            int hh = c >> 6, d = c & 63;
            ((unsigned short*)CoutVI)[((((size_t)(bb * 16 + hh) * 128 + (tt >> 4)) * 64 + d) << 4) + (tt & 15)] = hv;
          }
        } else {
          ((unsigned short*)Cout)[(size_t)row * N + col] = f2bf(vv);
        }
      }
    }
  }
}

// ---------------- causal flash attention, split-K two-wave merge ------------
// R16-verified form, launch_bounds (128,4): live state ~90 VGPR needs the
// 128-reg budget (R18's (128,6) forced VGPR=40 -> TB-scale spill).
__global__ __launch_bounds__(128, 4) void attn_kernel(
    const unsigned short* __restrict__ Q, const unsigned short* __restrict__ KI,
    const unsigned short* __restrict__ VI, unsigned short* __restrict__ O) {
  __shared__ __align__(16) unsigned short T[32 * 72];
  __shared__ __align__(16) float O1f[32][68];
  __shared__ float M1[64], L1[64];
  const int tid = threadIdx.x;
  const int w = tid >> 6, l = tid & 63;
  const int q32 = l & 31;
  const int g = l >> 5;
  const int x = blockIdx.x;
  const int bh = (x & 7) * 8 + (x >> 3);    // XCD-cluster same-head blocks
  const int b = bh >> 4, h = bh & 15;
  const int u = 63 - (int)blockIdx.y;       // heavy units first
  const int nt = u + 1;
  const int nh = (nt + 1) >> 1;             // wave 0 tile count
  const int jbeg = w ? nh : 0;
  const int jend = w ? nt : nh;
  const size_t tok0 = (size_t)b * SEQ;
  const size_t hoff = (size_t)h * 64;
  const unsigned short* Kp = KI + (size_t)bh * 4 * SEQ * 16;
  const unsigned short* Vp = VI + (size_t)bh * 128 * 64 * 16;

  const int q0 = u * 32;
  const int qg = q0 + q32;            // this lane's q row

  bf16x8 qf[4];
#pragma unroll
  for (int ks = 0; ks < 4; ++ks)
    qf[ks] = *(const bf16x8*)&Q[(tok0 + qg) * DM + hoff + ks * 16 + g * 8];

  f32x16 ot0 = {}, ot1 = {};
  float m = -3.0e38f, lden = 0.f;

  if (jbeg < jend) {
    bf16x8 kf[4], vf[4];
#pragma unroll
    for (int ks = 0; ks < 4; ++ks)
      kf[ks] = *(const bf16x8*)&Kp[((size_t)ks * SEQ + jbeg * 32 + q32) * 16 + g * 8];
#pragma unroll
    for (int dt = 0; dt < 2; ++dt)
#pragma unroll
      for (int s = 0; s < 2; ++s)
        vf[dt * 2 + s] = *(const bf16x8*)&Vp[(((size_t)jbeg * 2 + s) * 64 + dt * 32 + q32) * 16 + g * 8];

#pragma unroll 1
    for (int j = jbeg; j < jend; ++j) {
      f32x16 st = {};
      __builtin_amdgcn_s_setprio(1);
#pragma unroll
      for (int ks = 0; ks < 4; ++ks) st = mfma32(kf[ks], qf[ks], st);
      __builtin_amdgcn_s_setprio(0);
      const int jn = (j + 1 < jend) ? j + 1 : j;
      bf16x8 kn[4], vn[4];
#pragma unroll
      for (int ks = 0; ks < 4; ++ks)
        kn[ks] = *(const bf16x8*)&Kp[((size_t)ks * SEQ + jn * 32 + q32) * 16 + g * 8];
#pragma unroll
      for (int dt = 0; dt < 2; ++dt)
#pragma unroll
        for (int s = 0; s < 2; ++s)
          vn[dt * 2 + s] = *(const bf16x8*)&Vp[(((size_t)jn * 2 + s) * 64 + dt * 32 + q32) * 16 + g * 8];
      if (j == u) {
#pragma unroll
        for (int r = 0; r < 16; ++r) {
          int kg = j * 32 + (r & 3) + 8 * (r >> 2) + 4 * g;
          if (kg > qg) st[r] = -3.0e38f;
        }
      }
      float x0 = fmaxf(st[0], st[1]),  x1 = fmaxf(st[2], st[3]);
      float x2 = fmaxf(st[4], st[5]),  x3 = fmaxf(st[6], st[7]);
      float x4 = fmaxf(st[8], st[9]),  x5 = fmaxf(st[10], st[11]);
      float x6 = fmaxf(st[12], st[13]), x7 = fmaxf(st[14], st[15]);
      x0 = fmaxf(x0, x1); x2 = fmaxf(x2, x3); x4 = fmaxf(x4, x5); x6 = fmaxf(x6, x7);
      x0 = fmaxf(x0, x2); x4 = fmaxf(x4, x6);
      float pmax = fmaxf(x0, x4);
      if (__any(pmax - m > 8.0f)) {
        float pp = fmaxf(pmax, __shfl_xor(pmax, 32, 64));
        float mnew = fmaxf(m, pp);
        float sc = __expf(m - mnew);
#pragma unroll
        for (int r = 0; r < 16; ++r) { ot0[r] *= sc; ot1[r] *= sc; }
        lden *= sc;
        m = mnew;
      }
      float p[16];
#pragma unroll
      for (int r = 0; r < 16; ++r) p[r] = __expf(st[r] - m);
      {
        float s0 = p[0] + p[1], s1 = p[2] + p[3], s2 = p[4] + p[5], s3 = p[6] + p[7];
        float s4 = p[8] + p[9], s5 = p[10] + p[11], s6 = p[12] + p[13], s7 = p[14] + p[15];
        s0 += s1; s2 += s3; s4 += s5; s6 += s7;
        s0 += s2; s4 += s6;
        lden += s0 + s4;
      }
      unsigned c0 = cvtpk(p[0], p[1]),   c1 = cvtpk(p[2], p[3]);
      unsigned c2 = cvtpk(p[4], p[5]),   c3 = cvtpk(p[6], p[7]);
      unsigned c4 = cvtpk(p[8], p[9]),   c5 = cvtpk(p[10], p[11]);
      unsigned c6 = cvtpk(p[12], p[13]), c7 = cvtpk(p[14], p[15]);
      unsigned y0 = __shfl_xor(c0, 32, 64), y1 = __shfl_xor(c1, 32, 64);
      unsigned y2 = __shfl_xor(c2, 32, 64), y3 = __shfl_xor(c3, 32, 64);
      unsigned y4 = __shfl_xor(c4, 32, 64), y5 = __shfl_xor(c5, 32, 64);
      unsigned y6 = __shfl_xor(c6, 32, 64), y7 = __shfl_xor(c7, 32, 64);
      u32x4 f0 = { g ? y2 : c0, g ? y3 : c1, g ? c2 : y0, g ? c3 : y1 };
      u32x4 f1 = { g ? y6 : c4, g ? y7 : c5, g ? c6 : y4, g ? c7 : y5 };
      bf16x8 pb0 = __builtin_bit_cast(bf16x8, f0);
      bf16x8 pb1 = __builtin_bit_cast(bf16x8, f1);
      __builtin_amdgcn_s_setprio(1);
      ot0 = mfma32(vf[0], pb0, ot0);
      ot0 = mfma32(vf[1], pb1, ot0);
      ot1 = mfma32(vf[2], pb0, ot1);
      ot1 = mfma32(vf[3], pb1, ot1);
      __builtin_amdgcn_s_setprio(0);
#pragma unroll
      for (int ks = 0; ks < 4; ++ks) kf[ks] = kn[ks];
#pragma unroll
      for (int q = 0; q < 4; ++q) vf[q] = vn[q];
    }
  }
  // ---- split-K merge: wave 1 publishes partials, wave 0 combines ----
  if (w == 1) {
#pragma unroll
    for (int r = 0; r < 16; ++r) {
      O1f[r][l]      = ot0[r];
      O1f[16 + r][l] = ot1[r];
    }
    M1[l] = m;
    L1[l] = lden;
  }
  __syncthreads();
  if (w == 0) {
    float m1 = M1[l], l1c = L1[l];
    float mN = fmaxf(m, m1);
    float s0 = __expf(m - mN), s1 = __expf(m1 - mN);
    lden = lden * s0 + l1c * s1;
    lden += __shfl_xor(lden, 32, 64);
    float inv = 1.0f / lden;
#pragma unroll
    for (int r = 0; r < 16; ++r) {
      ot0[r] = ot0[r] * s0 + O1f[r][l] * s1;
      ot1[r] = ot1[r] * s0 + O1f[16 + r][l] * s1;
    }
#pragma unroll
    for (int r = 0; r < 16; ++r) {
      int d = (r & 3) + 8 * (r >> 2) + 4 * g;
      T[q32 * 72 + d]      = f2bf(ot0[r] * inv);
      T[q32 * 72 + 32 + d] = f2bf(ot1[r] * inv);
    }
#pragma unroll
    for (int j2 = 0; j2 < 4; ++j2) {
      int col = g * 32 + j2 * 8;
      u16x8 vv = *(const u16x8*)&T[q32 * 72 + col];
      *(u16x8*)&O[(tok0 + q0 + q32) * DM + hoff + col] = vv;
    }
  }
}

// ---------------- fused residual + LayerNorm ----------------
// MODE 0: bf16+bf16 -> bf16. MODE 1: bf16+f32 -> f32. MODE 2: bf16+bf16 -> f32.
template<int MODE>
__global__ __launch_bounds__(256) void ln_kernel(
    const unsigned short* __restrict__ Xa, const void* __restrict__ Xc,
    const float* __restrict__ g, const float* __restrict__ be,
    void* __restrict__ outp) {
  const int row = blockIdx.x, t = threadIdx.x;
  const size_t base = (size_t)row * DM + t * 4;
  float x[4];
  u16x4 a = *(const u16x4*)&Xa[base];
  if (MODE == 0 || MODE == 2) {
    u16x4 c = *(const u16x4*)&((const unsigned short*)Xc)[base];
#pragma unroll
    for (int i = 0; i < 4; ++i) x[i] = bf2f(a[i]) + bf2f(c[i]);
  } else {
    f32x4 c = *(const f32x4*)&((const float*)Xc)[base];
#pragma unroll
    for (int i = 0; i < 4; ++i) x[i] = bf2f(a[i]) + c[i];
  }
  float s = x[0] + x[1] + x[2] + x[3];
  float ss = x[0] * x[0] + x[1] * x[1] + x[2] * x[2] + x[3] * x[3];
#pragma unroll
  for (int m = 1; m < 64; m <<= 1) {
    s  += __shfl_xor(s, m, 64);
    ss += __shfl_xor(ss, m, 64);
  }
  __shared__ float red[8];
  const int w = t >> 6;
  if ((t & 63) == 0) { red[w * 2] = s; red[w * 2 + 1] = ss; }
  __syncthreads();
  s  = red[0] + red[2] + red[4] + red[6];
  ss = red[1] + red[3] + red[5] + red[7];
  const float mean = s * (1.0f / DM);
  const float var = ss * (1.0f / DM) - mean * mean;
  const float rstd = rsqrtf(var + 1e-5f);
  if (MODE == 0) {
    u16x4 o;
#pragma unroll
    for (int i = 0; i < 4; ++i) {
      int cx = t * 4 + i;
      o[i] = f2bf((x[i] - mean) * rstd * g[cx] + be[cx]);
    }
    *(u16x4*)&((unsigned short*)outp)[base] = o;
  } else {
    f32x4 o;
#pragma unroll
    for (int i = 0; i < 4; ++i) {
      int cx = t * 4 + i;
      o[i] = (x[i] - mean) * rstd * g[cx] + be[cx];
    }
    *(f32x4*)&((float*)outp)[base] = o;
  }
}

extern "C" void kernel_launch(void* const* d_in, const int* in_sizes, int n_in,
                              void* d_out, int out_size, void* d_ws, size_t ws_size,
                              hipStream_t stream) {
  (void)in_sizes; (void)n_in; (void)out_size; (void)ws_size;
  const float* kq  = (const float*)d_in[0];
  const float* v   = (const float*)d_in[1];
  const float* Wk  = (const float*)d_in[2];
  const float* bk  = (const float*)d_in[3];
  const float* Wq  = (const float*)d_in[4];
  const float* bq  = (const float*)d_in[5];
  const float* Wv  = (const float*)d_in[6];
  const float* bv  = (const float*)d_in[7];
  const float* W1  = (const float*)d_in[8];
  const float* b1  = (const float*)d_in[9];
  const float* W2  = (const float*)d_in[10];
  const float* b2  = (const float*)d_in[11];
  const float* g1  = (const float*)d_in[12];
  const float* be1 = (const float*)d_in[13];
  const float* g2  = (const float*)d_in[14];
  const float* be2 = (const float*)d_in[15];
  float* out = (float*)d_out;
  uint8_t* ws = (uint8_t*)d_ws;

  // Workspace overlay (lifetimes): region A [0, 73.4MB) holds X/Wqkv/Q/K/attn
  // which are all dead before FFN1; F1b reuses it. VIg + bqkv overlay the
  // F2b region (both dead before F2b is written by FFN2).
  unsigned short* Xb   = (unsigned short*)(ws + 0);
  unsigned short* Wkb  = (unsigned short*)(ws + 16777216);   // Wk|Wq|Wv contiguous
  unsigned short* Qb   = (unsigned short*)(ws + 23068672);
  unsigned short* Kb   = (unsigned short*)(ws + 39845888);
  unsigned short* Ab   = (unsigned short*)(ws + 56623104);
  unsigned short* F1b  = (unsigned short*)(ws + 0);          // overlay
  unsigned short* W1b  = (unsigned short*)(ws + 73400320);   // W1|W2 contiguous
  unsigned short* Vb   = (unsigned short*)(ws + 90177536);
  unsigned short* Hb   = (unsigned short*)(ws + 106954752);
  unsigned short* F2b  = (unsigned short*)(ws + 123731968);  // bf16 FFN2 out
  unsigned short* VIg  = (unsigned short*)(ws + 123731968);  // overlay (dead before F2b)
  float*          bqkv = (float*)(ws + 140509184);           // overlay, 12KB
  unsigned short* W2b  = W1b + 4194304;

  // Fused prologue: X concat-cast + all weight casts + bias concat, 1 launch.
  prologue<<<(TOTE + 3072 + 1023) / 1024, 256, 0, stream>>>(
      kq, v, Wk, Wq, Wv, W1, W2, bk, bq, bv, Xb, Wkb, W1b, bqkv);

  // Fused QKV: M=8192, N=3072, K=1024. BM=128 -> grid 64x12 = 768 (3/CU).
  gemm256<128, 5><<<768, 512, 98304, stream>>>(
      Xb, Wkb, bqkv, Kb, Qb, Vb, VIg, TOK, 3072, DM, 8, 12, 1);

  // Split-K attention: one block per (bh, unit), 2 waves split the key range.
  attn_kernel<<<dim3(64, 64), 128, 0, stream>>>(Qb, Kb, VIg, Ab);

  ln_kernel<0><<<TOK, 256, 0, stream>>>(Vb, Ab, g1, be1, Hb);

  // FFN1: 256x256 -> grid 32x16 = 512, XCD patch PR=8, PC=8, NPC=2. 128 KiB.
  gemm256<256, 2><<<512, 512, 131072, stream>>>(
      Hb, W1b, b1, F1b, nullptr, nullptr, nullptr, TOK, FFD, DM, 8, 8, 2);
  // FFN2: BM=128 -> grid 64x4 = 256 (full chip), PR=8, PC=4, NPC=1. 96 KiB.
  // bf16 output (EPI=1): halves FFN2 store + LN re-read traffic.
  gemm256<128, 1><<<256, 512, 98304, stream>>>(
      F1b, W2b, b2, F2b, nullptr, nullptr, nullptr, TOK, DM, FFD, 8, 4, 1);

  ln_kernel<2><<<TOK, 256, 0, stream>>>(Hb, F2b, g2, be2, out);
}